// Round 3
// baseline (306.408 us; speedup 1.0000x reference)
//
#include <hip/hip_runtime.h>

// Problem dims (fixed by reference)
#define C_DIM 2048
#define T_DIM 1024
#define R_DIM 32
#define K_DIM 128

#define NC 32                   // c-chunks for kernel B parallelism
#define KG 4                    // k's per thread (amortize uv load)
#define CCHUNK (C_DIM / NC)     // 64

// Kernel A: uv[c][t] = sum_r U[c][t][r] * V[r][t]  — wave-cooperative.
// 8 lanes per (c,t) pair; lane reads U[pair*32 + (lane&7)*4 .. +4) so a wave's
// 64 lanes load exactly 1 KiB CONTIGUOUS per instruction (vs the previous
// 128B-strided float4 that touched 64 cachelines per instr). r-reduction via
// 3x shfl_xor within the 8-lane group. V (128 KiB) is L2-resident.
__global__ void uv_kernel(const float* __restrict__ U, const float* __restrict__ V,
                          float* __restrict__ uv) {
    const int lane = threadIdx.x & 63;
    const int w = (blockIdx.x * blockDim.x + threadIdx.x) >> 6;  // global wave id
    const int r0 = (lane & 7) * 4;
    const int sub = lane >> 3;                                   // 0..7: pair within group
    const size_t pbase = (size_t)w * 64;                         // 64 pairs per wave

    const float* vb0 = V + (size_t)(r0 + 0) * T_DIM;
    const float* vb1 = V + (size_t)(r0 + 1) * T_DIM;
    const float* vb2 = V + (size_t)(r0 + 2) * T_DIM;
    const float* vb3 = V + (size_t)(r0 + 3) * T_DIM;

#pragma unroll
    for (int i = 0; i < 8; ++i) {
        size_t pair = pbase + i * 8 + sub;                       // = c*T + t
        int t = (int)(pair & (T_DIM - 1));
        float4 uq = *reinterpret_cast<const float4*>(U + pair * R_DIM + r0);
        float acc = uq.x * vb0[t] + uq.y * vb1[t] + uq.z * vb2[t] + uq.w * vb3[t];
        acc += __shfl_xor(acc, 1);
        acc += __shfl_xor(acc, 2);
        acc += __shfl_xor(acc, 4);
        if ((lane & 7) == 0) uv[pair] = acc;
    }
}

// Kernel B: partial[chunk][k][t] = sum_{c in chunk} uv[c][t] * X[k][c][t]
// Vectorized x4 over t: every load/store is float4 (1 KiB per wave-instr).
__global__ void partial_kernel(const float* __restrict__ X, const float* __restrict__ uv,
                               float* __restrict__ part) {
    int tid = blockIdx.x * blockDim.x + threadIdx.x;
    int t4    = tid & (T_DIM / 4 - 1);              // 0..255
    int kg    = (tid >> 8) & ((K_DIM / KG) - 1);    // 0..31
    int chunk = tid >> 13;                          // 0..NC-1
    int t0 = t4 * 4;
    int k0 = kg * KG;
    int c0 = chunk * CCHUNK;

    const size_t kstride = (size_t)C_DIM * T_DIM;   // stride between k planes
    const float* xb  = X + (size_t)k0 * kstride + (size_t)c0 * T_DIM + t0;
    const float* uvp = uv + (size_t)c0 * T_DIM + t0;

    float4 a0 = make_float4(0.f, 0.f, 0.f, 0.f);
    float4 a1 = a0, a2 = a0, a3 = a0;

#pragma unroll 4
    for (int c = 0; c < CCHUNK; ++c) {
        size_t off = (size_t)c * T_DIM;
        float4 w  = *reinterpret_cast<const float4*>(uvp + off);
        float4 x0 = *reinterpret_cast<const float4*>(xb + off);
        float4 x1 = *reinterpret_cast<const float4*>(xb + off + kstride);
        float4 x2 = *reinterpret_cast<const float4*>(xb + off + 2 * kstride);
        float4 x3 = *reinterpret_cast<const float4*>(xb + off + 3 * kstride);
        a0.x += w.x * x0.x; a0.y += w.y * x0.y; a0.z += w.z * x0.z; a0.w += w.w * x0.w;
        a1.x += w.x * x1.x; a1.y += w.y * x1.y; a1.z += w.z * x1.z; a1.w += w.w * x1.w;
        a2.x += w.x * x2.x; a2.y += w.y * x2.y; a2.z += w.z * x2.z; a2.w += w.w * x2.w;
        a3.x += w.x * x3.x; a3.y += w.y * x3.y; a3.z += w.z * x3.z; a3.w += w.w * x3.w;
    }
    float* p = part + ((size_t)chunk * K_DIM + k0) * T_DIM + t0;
    *reinterpret_cast<float4*>(p + 0 * T_DIM) = a0;
    *reinterpret_cast<float4*>(p + 1 * T_DIM) = a1;
    *reinterpret_cast<float4*>(p + 2 * T_DIM) = a2;
    *reinterpret_cast<float4*>(p + 3 * T_DIM) = a3;
}

// Kernel C: out[k][t] = sum_chunk partial[chunk][k][t], float4 over t
__global__ void reduce_kernel(const float* __restrict__ part, float* __restrict__ out) {
    int tid = blockIdx.x * blockDim.x + threadIdx.x;  // (k*T + t)/4
    size_t o = (size_t)tid * 4;
    float4 acc = make_float4(0.f, 0.f, 0.f, 0.f);
#pragma unroll
    for (int ch = 0; ch < NC; ++ch) {
        float4 v = *reinterpret_cast<const float4*>(part + (size_t)ch * K_DIM * T_DIM + o);
        acc.x += v.x; acc.y += v.y; acc.z += v.z; acc.w += v.w;
    }
    *reinterpret_cast<float4*>(out + o) = acc;
}

extern "C" void kernel_launch(void* const* d_in, const int* in_sizes, int n_in,
                              void* d_out, int out_size, void* d_ws, size_t ws_size,
                              hipStream_t stream) {
    // inputs: [0]=recording_index (unused), [1]=X (K,C,T), [2]=U (C,T,R), [3]=V (R,T)
    const float* X = (const float*)d_in[1];
    const float* U = (const float*)d_in[2];
    const float* V = (const float*)d_in[3];
    float* out = (float*)d_out;

    float* uv   = (float*)d_ws;                          // C*T floats = 8 MiB
    float* part = uv + (size_t)C_DIM * T_DIM;            // NC*K*T floats = 16 MiB

    // A: 64 pairs per wave, 4 waves per block -> C*T/256 pairs... grid:
    uv_kernel<<<C_DIM * T_DIM / (64 * 4), 256, 0, stream>>>(U, V, uv);
    partial_kernel<<<NC * (K_DIM / KG) * (T_DIM / 4) / 256, 256, 0, stream>>>(X, uv, part);
    reduce_kernel<<<K_DIM * T_DIM / 4 / 256, 256, 0, stream>>>(part, out);
}

// Round 4
// 251.553 us; speedup vs baseline: 1.2181x; 1.2181x over previous
//
#include <hip/hip_runtime.h>

// Problem dims (fixed by reference)
#define C_DIM 2048
#define T_DIM 1024
#define R_DIM 32
#define K_DIM 128

#define NC 16                   // c-chunks for kernel B parallelism (R2 config)
#define KG 4                    // k's per thread (amortize uv load)
#define CCHUNK (C_DIM / NC)     // 128

#define PAD 33                  // LDS row stride (floats): (lane+r)%32 -> 2-way, free

// Kernel A: uv[c][t] = sum_r U[c][t][r] * V[r][t]  — LDS-staged.
// Each block owns 256 consecutive (c,t) pairs = 32 KiB of U, staged with 8
// contiguous float4 loads per thread (1 KiB per wave-instr). LDS layout is
// pair-major with stride-33 padding so the compute phase's per-thread row
// reads are bank-conflict-free (2-way only). V loads are t-coalesced
// (256 B/instr, L2-resident); uv stores coalesced.
__global__ void uv_kernel(const float* __restrict__ U, const float* __restrict__ V,
                          float* __restrict__ uv) {
    __shared__ float su[256 * PAD];
    const int tid = threadIdx.x;
    const size_t p0 = (size_t)blockIdx.x * 256;      // first (c*T+t) pair of block

    // Stage: global float index j covers [0, 256*32); float4 never crosses a
    // 32-float pair boundary, so the padded scatter is per-element.
    const float* ub = U + p0 * R_DIM;
#pragma unroll
    for (int q = 0; q < 8; ++q) {
        int j = (q * 256 + tid) * 4;
        float4 vq = *reinterpret_cast<const float4*>(ub + j);
        float* d = su + (j >> 5) * PAD + (j & 31);
        d[0] = vq.x; d[1] = vq.y; d[2] = vq.z; d[3] = vq.w;
    }
    __syncthreads();

    const size_t pair = p0 + tid;                    // this thread's c*T + t
    const int t = (int)(pair & (T_DIM - 1));         // block t-span never wraps
    const float* vb = V + t;
    const float* s = su + tid * PAD;
    float acc = 0.f;
#pragma unroll
    for (int r = 0; r < R_DIM; ++r)
        acc += s[r] * vb[(size_t)r * T_DIM];
    uv[pair] = acc;
}

// Kernel B: partial[chunk][k][t] = sum_{c in chunk} uv[c][t] * X[k][c][t]
// Vectorized x4 over t: every load/store is float4 (1 KiB per wave-instr).
__global__ void partial_kernel(const float* __restrict__ X, const float* __restrict__ uv,
                               float* __restrict__ part) {
    int tid = blockIdx.x * blockDim.x + threadIdx.x;
    int t4    = tid & (T_DIM / 4 - 1);              // 0..255
    int kg    = (tid >> 8) & ((K_DIM / KG) - 1);    // 0..31
    int chunk = tid >> 13;                          // 0..NC-1
    int t0 = t4 * 4;
    int k0 = kg * KG;
    int c0 = chunk * CCHUNK;

    const size_t kstride = (size_t)C_DIM * T_DIM;   // stride between k planes
    const float* xb  = X + (size_t)k0 * kstride + (size_t)c0 * T_DIM + t0;
    const float* uvp = uv + (size_t)c0 * T_DIM + t0;

    float4 a0 = make_float4(0.f, 0.f, 0.f, 0.f);
    float4 a1 = a0, a2 = a0, a3 = a0;

#pragma unroll 4
    for (int c = 0; c < CCHUNK; ++c) {
        size_t off = (size_t)c * T_DIM;
        float4 w  = *reinterpret_cast<const float4*>(uvp + off);
        float4 x0 = *reinterpret_cast<const float4*>(xb + off);
        float4 x1 = *reinterpret_cast<const float4*>(xb + off + kstride);
        float4 x2 = *reinterpret_cast<const float4*>(xb + off + 2 * kstride);
        float4 x3 = *reinterpret_cast<const float4*>(xb + off + 3 * kstride);
        a0.x += w.x * x0.x; a0.y += w.y * x0.y; a0.z += w.z * x0.z; a0.w += w.w * x0.w;
        a1.x += w.x * x1.x; a1.y += w.y * x1.y; a1.z += w.z * x1.z; a1.w += w.w * x1.w;
        a2.x += w.x * x2.x; a2.y += w.y * x2.y; a2.z += w.z * x2.z; a2.w += w.w * x2.w;
        a3.x += w.x * x3.x; a3.y += w.y * x3.y; a3.z += w.z * x3.z; a3.w += w.w * x3.w;
    }
    float* p = part + ((size_t)chunk * K_DIM + k0) * T_DIM + t0;
    *reinterpret_cast<float4*>(p + 0 * T_DIM) = a0;
    *reinterpret_cast<float4*>(p + 1 * T_DIM) = a1;
    *reinterpret_cast<float4*>(p + 2 * T_DIM) = a2;
    *reinterpret_cast<float4*>(p + 3 * T_DIM) = a3;
}

// Kernel C: out[k][t] = sum_chunk partial[chunk][k][t], float4 over t
__global__ void reduce_kernel(const float* __restrict__ part, float* __restrict__ out) {
    int tid = blockIdx.x * blockDim.x + threadIdx.x;  // (k*T + t)/4
    size_t o = (size_t)tid * 4;
    float4 acc = make_float4(0.f, 0.f, 0.f, 0.f);
#pragma unroll
    for (int ch = 0; ch < NC; ++ch) {
        float4 v = *reinterpret_cast<const float4*>(part + (size_t)ch * K_DIM * T_DIM + o);
        acc.x += v.x; acc.y += v.y; acc.z += v.z; acc.w += v.w;
    }
    *reinterpret_cast<float4*>(out + o) = acc;
}

extern "C" void kernel_launch(void* const* d_in, const int* in_sizes, int n_in,
                              void* d_out, int out_size, void* d_ws, size_t ws_size,
                              hipStream_t stream) {
    // inputs: [0]=recording_index (unused), [1]=X (K,C,T), [2]=U (C,T,R), [3]=V (R,T)
    const float* X = (const float*)d_in[1];
    const float* U = (const float*)d_in[2];
    const float* V = (const float*)d_in[3];
    float* out = (float*)d_out;

    float* uv   = (float*)d_ws;                          // C*T floats = 8 MiB
    float* part = uv + (size_t)C_DIM * T_DIM;            // NC*K*T floats = 8 MiB

    uv_kernel<<<C_DIM * T_DIM / 256, 256, 0, stream>>>(U, V, uv);
    partial_kernel<<<NC * (K_DIM / KG) * (T_DIM / 4) / 256, 256, 0, stream>>>(X, uv, part);
    reduce_kernel<<<K_DIM * T_DIM / 4 / 256, 256, 0, stream>>>(part, out);
}